// Round 10
// baseline (319.222 us; speedup 1.0000x reference)
//
#include <hip/hip_runtime.h>
#include <hip/hip_bf16.h>

#define N_NODES 100000
#define N_EDGES 1600000
#define DIM_IN  256
#define DIM_H   128

#define NBKT 782          // ceil(N_NODES / 128) buckets of 128 nodes
#define CPAD 16           // ints per padded counter (one cacheline)
#define CAP  4096         // records per bucket (mean 2048, sd ~45 -> safe)
#define EPB2 4096         // edges per bin block (256 thr x 16)
#define NBLK2 ((N_EDGES + EPB2 - 1) / EPB2)   // 391
#define GEMM_BLKS ((N_NODES + 63) / 64)       // 1563

typedef __attribute__((ext_vector_type(8))) short short8;
typedef __attribute__((ext_vector_type(4))) float f32x4;

__device__ __forceinline__ int get_src(const int* e, int is64, int i) {
  return is64 ? e[2 * i] : e[i];
}
__device__ __forceinline__ int get_dst(const int* e, int is64, int i) {
  return is64 ? e[2 * (N_EDGES + i)] : e[N_EDGES + i];
}

// ---------------------------------------------------------------- bf16 utils
__device__ __forceinline__ ushort f2bf(float f) {
  unsigned u = __float_as_uint(f);
  unsigned r = (u + 0x7fffu + ((u >> 16) & 1u)) >> 16;
  return (ushort)r;
}
__device__ __forceinline__ float bf2f(ushort h) {
  return __uint_as_float(((unsigned)h) << 16);
}

__device__ __forceinline__ void load8(const float* p, float* o) {
  float4 a = reinterpret_cast<const float4*>(p)[0];
  float4 b = reinterpret_cast<const float4*>(p)[1];
  o[0] = a.x; o[1] = a.y; o[2] = a.z; o[3] = a.w;
  o[4] = b.x; o[5] = b.y; o[6] = b.z; o[7] = b.w;
}

__device__ __forceinline__ void cvt_split(const float* v, short8& h, short8& l) {
#pragma unroll
  for (int j = 0; j < 8; ++j) {
    ushort hb = f2bf(v[j]);
    ushort lb = f2bf(v[j] - bf2f(hb));
    h[j] = (short)hb;
    l[j] = (short)lb;
  }
}

// Blocks 0..15: split Wi[256x128] into MFMA B-fragment planes (hi, lo).
// Block 16: collapsed tail weights Wcc = W1@(W2@Wh), c1 = b1@(W2@Wh),
//           bc = b2@Wh + bh  (Wcc[0..255], [256..257], [258..259]).
// Block 17: zero bucket counters.  Blocks 18+: zero deg.
__global__ __launch_bounds__(256)
void k_prep(const float* __restrict__ Wi, const float* __restrict__ W1,
            const float* __restrict__ W2, const float* __restrict__ Wh,
            const float* __restrict__ b1, const float* __restrict__ b2,
            const float* __restrict__ bh, ushort* __restrict__ outHi,
            float* __restrict__ Wcc, int* __restrict__ bcnt,
            int* __restrict__ deg) {
  __shared__ float Wc2s[DIM_H][2];
  constexpr int CH = DIM_IN / 32;   // 8
  if (blockIdx.x >= 18) {
    int i = (blockIdx.x - 18) * 256 + threadIdx.x;
    if (i < N_NODES) deg[i] = 0;
    return;
  }
  if (blockIdx.x == 17) {
    for (int i = threadIdx.x; i < NBKT * CPAD; i += 256) bcnt[i] = 0;
    return;
  }
  if (blockIdx.x == 16) {
    const int t = threadIdx.x;
    const int i = t >> 1, j = t & 1;
    float s = 0.f;
#pragma unroll 4
    for (int m = 0; m < DIM_H; ++m) s += W2[(size_t)i * DIM_H + m] * Wh[m * 2 + j];
    Wc2s[i][j] = s;
    __syncthreads();
    float c = 0.f;
#pragma unroll 4
    for (int k = 0; k < DIM_H; ++k) c += W1[(size_t)i * DIM_H + k] * Wc2s[k][j];
    Wcc[i * 2 + j] = c;
    if (t < 2) {
      float a = 0.f, b = 0.f;
      for (int k = 0; k < DIM_H; ++k) {
        a += b1[k] * Wc2s[k][t];
        b += b2[k] * Wh[k * 2 + t];
      }
      Wcc[256 + t] = a;           // c1
      Wcc[258 + t] = b + bh[t];   // bc
    }
    return;
  }
  int idx = blockIdx.x * 256 + threadIdx.x;   // < CH*512 = 4096
  int n  = idx & 15;
  int qq = (idx >> 4) & 3;
  int nt = (idx >> 6) & 7;
  int c  = idx >> 9;
  int col = nt * 16 + n;
  short8 h8, l8;
#pragma unroll
  for (int j = 0; j < 8; ++j) {
    float v = Wi[(size_t)(c * 32 + qq * 8 + j) * DIM_H + col];
    ushort hb = f2bf(v);
    ushort lb = f2bf(v - bf2f(hb));
    h8[j] = (short)hb;
    l8[j] = (short)lb;
  }
  ((short8*)outHi)[idx] = h8;
  ((short8*)outHi)[CH * 512 + idx] = l8;
}

// ---------------- FUSED: blocks [0, NBLK2) = edge binning (+deg atomics);
// blocks [NBLK2, NBLK2+GEMM_BLKS) = MFMA GEMM emitting RAW z (no dinv dep).
// The two halves are independent -> they overlap on the device.
__global__ __launch_bounds__(256, 4)
void k_main(const int* __restrict__ eidx, const float* __restrict__ A,
            const ushort* __restrict__ Bfrag, const float* __restrict__ bias,
            const float* __restrict__ Wcc, int* __restrict__ bcnt,
            unsigned* __restrict__ ebuf, int* __restrict__ deg,
            float2* __restrict__ ztmp) {
  __shared__ __align__(16) char smem[16384];
  const int tid = threadIdx.x;

  if (blockIdx.x < NBLK2) {
    // ---------------- binning branch (256 thr, 16 edges each)
    int* hist = (int*)smem;          // NBKT ints
    int* curL = hist + NBKT;         // NBKT ints
    int* sorp = curL + NBKT;
    if (tid == 0) *sorp = 0;
    for (int i = tid; i < NBKT; i += 256) hist[i] = 0;
    __syncthreads();
    if (eidx[2 * tid + 1] != 0) atomicOr(sorp, 1);
    __syncthreads();
    const int is64 = (*sorp == 0);

    unsigned rec[16];
    int bkt[16];
#pragma unroll
    for (int j = 0; j < 16; ++j) {
      int e = blockIdx.x * EPB2 + j * 256 + tid;
      bkt[j] = -1;
      rec[j] = 0;
      if (e < N_EDGES) {
        unsigned s = (unsigned)get_src(eidx, is64, e);
        unsigned d = (unsigned)get_dst(eidx, is64, e);
        if (s < N_NODES && d < N_NODES) {
          bkt[j] = (int)(d >> 7);
          rec[j] = s | ((d & 127u) << 17);
          atomicAdd(&hist[bkt[j]], 1);
          atomicAdd(&deg[d], 1);             // per-node degree (L2 atomic)
        }
      }
    }
    __syncthreads();
    for (int i = tid; i < NBKT; i += 256) {
      int h = hist[i];
      curL[i] = h ? atomicAdd(&bcnt[i * CPAD], h) : 0;
    }
    __syncthreads();
#pragma unroll
    for (int j = 0; j < 16; ++j) {
      if (bkt[j] >= 0) {
        int pos = atomicAdd(&curL[bkt[j]], 1);
        ebuf[(size_t)bkt[j] * CAP + pos] = rec[j];
      }
    }
    return;
  }

  // ---------------- GEMM branch (r8 structure; raw-z epilogue)
  constexpr int CH = DIM_IN / 32;   // 8
  const int m0 = (blockIdx.x - NBLK2) * 64;
  const int wave = tid >> 6, lane = tid & 63;
  const int m_l = lane & 15, quad = lane >> 4;
  const int rs = tid >> 2, q = tid & 3;

  f32x4 acc[2][4];
#pragma unroll
  for (int i = 0; i < 2; ++i)
#pragma unroll
    for (int j = 0; j < 4; ++j) acc[i][j] = (f32x4){0.f, 0.f, 0.f, 0.f};

  const short8* Bhi8 = (const short8*)Bfrag;
  const short8* Blo8 = Bhi8 + CH * 512;
  short8* Ah = (short8*)smem;            // [2][256] granules (8 KB)
  short8* Al = (short8*)(smem + 8192);   // [2][256] granules (8 KB)

  const int gr = m0 + rs;
  const float* Ap = &A[(size_t)((gr < N_NODES) ? gr : (N_NODES - 1)) * DIM_IN + q * 8];
  const int went = (rs >> 4) * 64 + q * 16 + ((rs & 15) ^ (q << 2));   // swizzled write
  const int rent = quad * 16 + (m_l ^ (quad << 2));                     // + mt*64 on read

  {
    float v[8];
    load8(Ap, v);
    short8 h, l;
    cvt_split(v, h, l);
    Ah[went] = h;
    Al[went] = l;
  }
  const int bq = quad * 16 + m_l;
  short8 bh0 = Bhi8[(wave * 2 + 0) * 64 + bq];
  short8 bl0 = Blo8[(wave * 2 + 0) * 64 + bq];
  short8 bh1 = Bhi8[(wave * 2 + 1) * 64 + bq];
  short8 bl1 = Blo8[(wave * 2 + 1) * 64 + bq];
  __syncthreads();

#pragma unroll
  for (int c = 0; c < CH; ++c) {
    const int cur = c & 1, nxt = cur ^ 1;
    float vn[8];
    short8 nbh0, nbl0, nbh1, nbl1;
    if (c + 1 < CH) {
      load8(Ap + (c + 1) * 32, vn);
      const int b0 = ((c + 1) * 8 + wave * 2 + 0) * 64 + bq;
      const int b1 = ((c + 1) * 8 + wave * 2 + 1) * 64 + bq;
      nbh0 = Bhi8[b0]; nbl0 = Blo8[b0];
      nbh1 = Bhi8[b1]; nbl1 = Blo8[b1];
    }
    const short8* AhC = Ah + cur * 256;
    const short8* AlC = Al + cur * 256;
#pragma unroll
    for (int mt = 0; mt < 4; ++mt) {
      short8 ahi = AhC[mt * 64 + rent];
      short8 alo = AlC[mt * 64 + rent];
      acc[0][mt] = __builtin_amdgcn_mfma_f32_16x16x32_bf16(ahi, bh0, acc[0][mt], 0, 0, 0);
      acc[0][mt] = __builtin_amdgcn_mfma_f32_16x16x32_bf16(ahi, bl0, acc[0][mt], 0, 0, 0);
      acc[0][mt] = __builtin_amdgcn_mfma_f32_16x16x32_bf16(alo, bh0, acc[0][mt], 0, 0, 0);
      acc[1][mt] = __builtin_amdgcn_mfma_f32_16x16x32_bf16(ahi, bh1, acc[1][mt], 0, 0, 0);
      acc[1][mt] = __builtin_amdgcn_mfma_f32_16x16x32_bf16(ahi, bl1, acc[1][mt], 0, 0, 0);
      acc[1][mt] = __builtin_amdgcn_mfma_f32_16x16x32_bf16(alo, bh1, acc[1][mt], 0, 0, 0);
    }
    if (c + 1 < CH) {
      short8 h, l;
      cvt_split(vn, h, l);
      Ah[nxt * 256 + went] = h;
      Al[nxt * 256 + went] = l;
      bh0 = nbh0; bl0 = nbl0; bh1 = nbh1; bl1 = nbl1;
    }
    __syncthreads();
  }

  // ---- fused epilogue: p = relu(acc + bias) @ Wcc, reduced over 128 cols
  float p0[4][4], p1[4][4];
#pragma unroll
  for (int mt = 0; mt < 4; ++mt)
#pragma unroll
    for (int r = 0; r < 4; ++r) { p0[mt][r] = 0.f; p1[mt][r] = 0.f; }
#pragma unroll
  for (int ntl = 0; ntl < 2; ++ntl) {
    const int colg = (wave * 2 + ntl) * 16 + m_l;
    const float bv = bias[colg];
    const float w0 = Wcc[colg * 2 + 0];
    const float w1 = Wcc[colg * 2 + 1];
#pragma unroll
    for (int mt = 0; mt < 4; ++mt)
#pragma unroll
      for (int r = 0; r < 4; ++r) {
        float hv = fmaxf(acc[ntl][mt][r] + bv, 0.f);   // relu(h1)
        p0[mt][r] += hv * w0;
        p1[mt][r] += hv * w1;
      }
  }
#pragma unroll
  for (int o = 1; o < 16; o <<= 1) {
#pragma unroll
    for (int mt = 0; mt < 4; ++mt)
#pragma unroll
      for (int r = 0; r < 4; ++r) {
        p0[mt][r] += __shfl_xor(p0[mt][r], o);
        p1[mt][r] += __shfl_xor(p1[mt][r], o);
      }
  }
  // cross-wave reduction via LDS (staging dead after final barrier above)
  float* zred = (float*)smem;   // [j][wave][quad][mt][r] = [2][4][4][4][4]
  if (m_l == 0) {
#pragma unroll
    for (int mt = 0; mt < 4; ++mt)
#pragma unroll
      for (int r = 0; r < 4; ++r) {
        zred[(((0 * 4 + wave) * 4 + quad) * 4 + mt) * 4 + r] = p0[mt][r];
        zred[(((1 * 4 + wave) * 4 + quad) * 4 + mt) * 4 + r] = p1[mt][r];
      }
  }
  __syncthreads();
  if (tid < 64) {
    const int mt = tid >> 4, qd = (tid >> 2) & 3, r = tid & 3;
    const int rowg = m0 + tid;
    if (rowg < N_NODES) {
      float s0 = 0.f, s1 = 0.f;
#pragma unroll
      for (int w = 0; w < 4; ++w) {
        s0 += zred[(((0 * 4 + w) * 4 + qd) * 4 + mt) * 4 + r];
        s1 += zred[(((1 * 4 + w) * 4 + qd) * 4 + mt) * 4 + r];
      }
      ztmp[rowg] = make_float2(s0, s1);   // RAW z (dinv applied in k_scale)
    }
  }
}

// ---------------- scale: tbl[n] = (dinv*z0, dinv*z1, dinv, 0) --------------
__global__ __launch_bounds__(256)
void k_scale(const int* __restrict__ deg, const float2* __restrict__ ztmp,
             float4* __restrict__ tbl) {
  int n = blockIdx.x * 256 + threadIdx.x;
  if (n < N_NODES) {
    float dn = rsqrtf(1.0f + (float)deg[n]);
    float2 z = ztmp[n];
    tbl[n] = make_float4(dn * z.x, dn * z.y, dn, 0.f);
  }
}

// ---------------- pass 1, bucket-centric: LDS accumulate 3 floats/edge.
// yt[d] = dinv²·(z[d]+Σz[s]); g[d] = dinv·(dinv+Σdinv[s]).
__global__ __launch_bounds__(256)
void k_aggr1B(const int* __restrict__ bcnt, const unsigned* __restrict__ ebuf,
              const float4* __restrict__ tbl, float2* __restrict__ tb2,
              float* __restrict__ g) {
  __shared__ float acc[128][4];
  const int b = blockIdx.x, t = threadIdx.x;
  if (t < 128) { acc[t][0] = 0.f; acc[t][1] = 0.f; acc[t][2] = 0.f; }
  __syncthreads();
  const int cnt = bcnt[b * CPAD];
  const unsigned* eb = ebuf + (size_t)b * CAP;
  for (int i = t; i < cnt; i += 256) {
    unsigned r = eb[i];
    float4 v = tbl[r & 0x1FFFFu];
    int d = r >> 17;
    atomicAdd(&acc[d][0], v.x);
    atomicAdd(&acc[d][1], v.y);
    atomicAdd(&acc[d][2], v.z);
  }
  __syncthreads();
  if (t < 128) {
    int node = (b << 7) + t;
    if (node < N_NODES) {
      float4 self = tbl[node];
      float dn = self.z;
      tb2[node] = make_float2(dn * dn * (acc[t][0] + self.x),
                              dn * dn * (acc[t][1] + self.y));
      g[node] = dn * (acc[t][2] + self.z);
    }
  }
}

// ---------------- pass 2, bucket-centric: out = bc + dinv·(yt+Σyt) + g·c1.
// tail = {c1[0],c1[1],bc[0],bc[1]}
__global__ __launch_bounds__(256)
void k_aggr2B(const int* __restrict__ bcnt, const unsigned* __restrict__ ebuf,
              const float2* __restrict__ tb2, const float4* __restrict__ tbl,
              const float* __restrict__ g, const float* __restrict__ tail,
              float* __restrict__ out) {
  __shared__ float acc[128][2];
  const int b = blockIdx.x, t = threadIdx.x;
  if (t < 128) { acc[t][0] = 0.f; acc[t][1] = 0.f; }
  __syncthreads();
  const int cnt = bcnt[b * CPAD];
  const unsigned* eb = ebuf + (size_t)b * CAP;
  for (int i = t; i < cnt; i += 256) {
    unsigned r = eb[i];
    float2 v = tb2[r & 0x1FFFFu];
    int d = r >> 17;
    atomicAdd(&acc[d][0], v.x);
    atomicAdd(&acc[d][1], v.y);
  }
  __syncthreads();
  if (t < 128) {
    int node = (b << 7) + t;
    if (node < N_NODES) {
      float2 self = tb2[node];
      float dn = tbl[node].z;
      float gv = g[node];
      float o0 = dn * (acc[t][0] + self.x) + gv * tail[0] + tail[2];
      float o1 = dn * (acc[t][1] + self.y) + gv * tail[1] + tail[3];
      reinterpret_cast<float2*>(out)[node] = make_float2(o0, o1);
    }
  }
}

// --------------------------------------------- fp32 fallback (small ws) ----
__global__ __launch_bounds__(1024) void k_detect(const int* __restrict__ e,
                                                 int* __restrict__ flag) {
  __shared__ int s;
  if (threadIdx.x == 0) s = 0;
  __syncthreads();
  atomicOr(&s, e[2 * threadIdx.x + 1]);
  __syncthreads();
  if (threadIdx.x == 0) *flag = (s == 0) ? 1 : 0;
}

__global__ __launch_bounds__(256) void k_zero(int* __restrict__ p, int n) {
  int i = blockIdx.x * 256 + threadIdx.x;
  if (i < n) p[i] = 0;
}

__global__ __launch_bounds__(256) void k_count(const int* __restrict__ eidx,
                                               const int* __restrict__ flag,
                                               int* __restrict__ off) {
  int e = blockIdx.x * 256 + threadIdx.x;
  int is64 = *flag;
  if (e < N_EDGES) {
    unsigned d = (unsigned)get_dst(eidx, is64, e);
    if (d < N_NODES) atomicAdd(&off[d], 1);
  }
}

__global__ __launch_bounds__(256) void k_dinv_old(const int* __restrict__ off,
                                                  float* __restrict__ dinv) {
  int i = blockIdx.x * 256 + threadIdx.x;
  if (i < N_NODES) dinv[i] = rsqrtf(1.0f + (float)off[i]);
}

template <int K>
__global__ __launch_bounds__(256)
void k_gemm(const float* __restrict__ A, const float* __restrict__ B,
            const float* __restrict__ bias, const float* __restrict__ scale,
            float* __restrict__ C, const int do_relu) {
  __shared__ float As[64][33];
  const int tid = threadIdx.x;
  const int tx = tid & 15;
  const int ty = tid >> 4;
  const int m0 = blockIdx.x * 64;

  float acc[4][8];
#pragma unroll
  for (int i = 0; i < 4; ++i)
#pragma unroll
    for (int j = 0; j < 8; ++j) acc[i][j] = 0.f;

  const int rs = tid >> 2;
  const int ks = (tid & 3) * 8;

  for (int k0 = 0; k0 < K; k0 += 32) {
    float av8[8];
    const int gm = m0 + rs;
    if (gm < N_NODES) {
      load8(&A[(size_t)gm * K + k0 + ks], av8);
    } else {
#pragma unroll
      for (int j = 0; j < 8; ++j) av8[j] = 0.f;
    }
    __syncthreads();
#pragma unroll
    for (int j = 0; j < 8; ++j) As[rs][ks + j] = av8[j];
    __syncthreads();

    const float* Bp = B + (size_t)k0 * DIM_H + tx * 8;
#pragma unroll 4
    for (int k = 0; k < 32; ++k) {
      float bv[8];
      load8(Bp + (size_t)k * DIM_H, bv);
      float av[4];
#pragma unroll
      for (int rr = 0; rr < 4; ++rr) av[rr] = As[ty * 4 + rr][k];
#pragma unroll
      for (int rr = 0; rr < 4; ++rr)
#pragma unroll
        for (int cc = 0; cc < 8; ++cc)
          acc[rr][cc] = fmaf(av[rr], bv[cc], acc[rr][cc]);
    }
  }

  float bs[8];
  if (bias) {
    load8(bias + tx * 8, bs);
  } else {
#pragma unroll
    for (int j = 0; j < 8; ++j) bs[j] = 0.f;
  }
#pragma unroll
  for (int rr = 0; rr < 4; ++rr) {
    const int gm = m0 + ty * 4 + rr;
    if (gm < N_NODES) {
      float sc = scale ? scale[gm] : 1.0f;
      float v[8];
#pragma unroll
      for (int cc = 0; cc < 8; ++cc) {
        float t = acc[rr][cc] + bs[cc];
        if (do_relu) t = fmaxf(t, 0.f);
        v[cc] = t * sc;
      }
      float* Cp = &C[(size_t)gm * DIM_H + tx * 8];
      reinterpret_cast<float4*>(Cp)[0] = make_float4(v[0], v[1], v[2], v[3]);
      reinterpret_cast<float4*>(Cp)[1] = make_float4(v[4], v[5], v[6], v[7]);
    }
  }
}

__global__ __launch_bounds__(256)
void k_aggr_init(const float* __restrict__ t, const float* __restrict__ dinv,
                 const float* __restrict__ bias, float* __restrict__ h) {
  int idx = blockIdx.x * 256 + threadIdx.x;
  if (idx < N_NODES * DIM_H) {
    int i = idx >> 7;
    int c = idx & 127;
    float d = dinv[i];
    h[idx] = bias[c] + t[idx] * d * d;
  }
}

__global__ __launch_bounds__(256)
void k_aggr_edges(const int* __restrict__ eidx, const int* __restrict__ flag,
                  const float* __restrict__ t, const float* __restrict__ dinv,
                  float* __restrict__ h) {
  int e = blockIdx.x * 2 + (threadIdx.x >> 7);
  int c = threadIdx.x & 127;
  int is64 = *flag;
  if (e < N_EDGES) {
    unsigned s = (unsigned)get_src(eidx, is64, e);
    unsigned d = (unsigned)get_dst(eidx, is64, e);
    if (s < N_NODES && d < N_NODES) {
      float nrm = dinv[s] * dinv[d];
      unsafeAtomicAdd(&h[(size_t)d * DIM_H + c], t[(size_t)s * DIM_H + c] * nrm);
    }
  }
}

__global__ __launch_bounds__(256)
void k_head_f32(const float* __restrict__ h, const float* __restrict__ Wh,
                const float* __restrict__ bh, float* __restrict__ out) {
  int node = blockIdx.x * 4 + (threadIdx.x >> 6);
  int lane = threadIdx.x & 63;
  if (node >= N_NODES) return;
  float h0 = h[(size_t)node * DIM_H + lane];
  float h1 = h[(size_t)node * DIM_H + 64 + lane];
  float s0 = h0 * Wh[lane * 2 + 0] + h1 * Wh[(lane + 64) * 2 + 0];
  float s1 = h0 * Wh[lane * 2 + 1] + h1 * Wh[(lane + 64) * 2 + 1];
#pragma unroll
  for (int off = 32; off > 0; off >>= 1) {
    s0 += __shfl_down(s0, off);
    s1 += __shfl_down(s1, off);
  }
  if (lane == 0) {
    reinterpret_cast<float2*>(out)[node] = make_float2(s0 + bh[0], s1 + bh[1]);
  }
}

// ---------------------------------------------------------------- launch
extern "C" void kernel_launch(void* const* d_in, const int* in_sizes, int n_in,
                              void* d_out, int out_size, void* d_ws, size_t ws_size,
                              hipStream_t stream) {
  (void)in_sizes; (void)n_in; (void)out_size;
  const int* eidx = (const int*)d_in[0];
  const float* x  = (const float*)d_in[1];
  const float* Wi = (const float*)d_in[2];
  const float* bi = (const float*)d_in[3];
  const float* W1 = (const float*)d_in[4];
  const float* b1 = (const float*)d_in[5];
  const float* W2 = (const float*)d_in[6];
  const float* b2 = (const float*)d_in[7];
  const float* Wh = (const float*)d_in[8];
  const float* bh = (const float*)d_in[9];
  float* out = (float*)d_out;

  const int gE  = (N_EDGES + 255) / 256;
  const int gM  = (N_NODES + 63) / 64;
  const int gW  = (N_NODES + 3) / 4;
  const int gN256 = (N_NODES + 255) / 256;   // 391

  char* ws = (char*)d_ws;

  const size_t need1 = 17001600;

  if (ws_size >= need1) {
    float*    Wcc  = (float*)(ws + 4096);       // 260 floats
    ushort*   bfWi = (ushort*)(ws + 8192);      // 131072 B -> 139264
    int*      bcnt = (int*)(ws + 139264);       // 50048 B  -> 189312
    int*      deg  = (int*)(ws + 189312);       // 400000 B -> 589312
    float2*   ztmp = (float2*)(ws + 589312);    // 800000 B -> 1389312
    float4*   tbl  = (float4*)(ws + 1389312);   // 1600000 B -> 2989312
    float2*   tb2  = (float2*)(ws + 2989312);   // 800000 B -> 3789312
    float*    g    = (float*)(ws + 3789312);    // 400000 B -> 4189312
    unsigned* ebuf = (unsigned*)(ws + 4189312); // 12812288 B -> 17001600

    // K1: weight prep + bcnt zero + deg zero
    k_prep<<<18 + gN256, 256, 0, stream>>>(Wi, W1, W2, Wh, b1, b2, bh,
                                           bfWi, Wcc, bcnt, deg);
    // K2: fused {edge binning + deg atomics} || {GEMM -> raw z}
    k_main<<<NBLK2 + GEMM_BLKS, 256, 0, stream>>>(eidx, x, bfWi, bi, Wcc,
                                                  bcnt, ebuf, deg, ztmp);
    // K3: tbl = (dinv*z0, dinv*z1, dinv, 0)
    k_scale<<<gN256, 256, 0, stream>>>(deg, ztmp, tbl);
    // K4/K5: bucket-centric aggregations
    k_aggr1B<<<NBKT, 256, 0, stream>>>(bcnt, ebuf, tbl, tb2, g);
    k_aggr2B<<<NBKT, 256, 0, stream>>>(bcnt, ebuf, tb2, tbl, g, Wcc + 256, out);
  } else {
    // fallback: fp32 atomic-scatter path (~103 MB)
    const int gN  = (N_NODES + 255) / 256;
    int*   flag = (int*)ws;
    int*   off  = (int*)(ws + 4096);
    float* dinv = (float*)(ws + 404480);
    float* fbA  = (float*)(ws + 804864);
    float* fbB  = (float*)(ws + 804864 + (size_t)N_NODES * DIM_H * 4);
    const int gNH = (N_NODES * DIM_H + 255) / 256;
    const int gE2 = (N_EDGES + 1) / 2;
    k_detect<<<1, 1024, 0, stream>>>(eidx, flag);
    k_zero<<<gN, 256, 0, stream>>>(off, N_NODES);
    k_count<<<gE, 256, 0, stream>>>(eidx, flag, off);
    k_dinv_old<<<gN, 256, 0, stream>>>(off, dinv);

    k_gemm<DIM_IN><<<gM, 256, 0, stream>>>(x, Wi, bi, nullptr, fbA, 1);
    k_gemm<DIM_H><<<gM, 256, 0, stream>>>(fbA, W1, nullptr, nullptr, fbB, 0);
    k_aggr_init<<<gNH, 256, 0, stream>>>(fbB, dinv, b1, fbA);
    k_aggr_edges<<<gE2, 256, 0, stream>>>(eidx, flag, fbB, dinv, fbA);
    k_gemm<DIM_H><<<gM, 256, 0, stream>>>(fbA, W2, nullptr, nullptr, fbB, 0);
    k_aggr_init<<<gNH, 256, 0, stream>>>(fbB, dinv, b2, fbA);
    k_aggr_edges<<<gE2, 256, 0, stream>>>(eidx, flag, fbB, dinv, fbA);
    k_head_f32<<<gW, 256, 0, stream>>>(fbA, Wh, bh, out);
  }
}

// Round 11
// 285.790 us; speedup vs baseline: 1.1170x; 1.1170x over previous
//
#include <hip/hip_runtime.h>
#include <hip/hip_bf16.h>

#define N_NODES 100000
#define N_EDGES 1600000
#define DIM_IN  256
#define DIM_H   128

#define NBKT 782          // ceil(N_NODES / 128) buckets of 128 nodes
#define CPAD 16           // ints per padded counter (one cacheline)
#define CAP  4096         // records per bucket (mean 2048, sd ~45 -> safe)
#define EPB  8192         // edges per build block
#define NBLK ((N_EDGES + EPB - 1) / EPB)   // 196

typedef __attribute__((ext_vector_type(8))) short short8;
typedef __attribute__((ext_vector_type(4))) float f32x4;

__device__ __forceinline__ int get_src(const int* e, int is64, int i) {
  return is64 ? e[2 * i] : e[i];
}
__device__ __forceinline__ int get_dst(const int* e, int is64, int i) {
  return is64 ? e[2 * (N_EDGES + i)] : e[N_EDGES + i];
}

// ---------------------------------------------------------------- bf16 utils
__device__ __forceinline__ ushort f2bf(float f) {
  unsigned u = __float_as_uint(f);
  unsigned r = (u + 0x7fffu + ((u >> 16) & 1u)) >> 16;
  return (ushort)r;
}
__device__ __forceinline__ float bf2f(ushort h) {
  return __uint_as_float(((unsigned)h) << 16);
}

__device__ __forceinline__ void load8(const float* p, float* o) {
  float4 a = reinterpret_cast<const float4*>(p)[0];
  float4 b = reinterpret_cast<const float4*>(p)[1];
  o[0] = a.x; o[1] = a.y; o[2] = a.z; o[3] = a.w;
  o[4] = b.x; o[5] = b.y; o[6] = b.z; o[7] = b.w;
}

__device__ __forceinline__ void cvt_split(const float* v, short8& h, short8& l) {
#pragma unroll
  for (int j = 0; j < 8; ++j) {
    ushort hb = f2bf(v[j]);
    ushort lb = f2bf(v[j] - bf2f(hb));
    h[j] = (short)hb;
    l[j] = (short)lb;
  }
}

// Blocks 0..15: split Wi[256x128] into MFMA B-fragment planes (hi, lo).
// Block 16: collapsed tail weights Wcc = W1@(W2@Wh), c1 = b1@(W2@Wh),
//           bc = b2@Wh + bh  (stored Wcc[0..255], [256..257], [258..259]).
// Block 17: zero the bucket counters.
__global__ __launch_bounds__(256)
void k_prep(const float* __restrict__ Wi, const float* __restrict__ W1,
            const float* __restrict__ W2, const float* __restrict__ Wh,
            const float* __restrict__ b1, const float* __restrict__ b2,
            const float* __restrict__ bh, ushort* __restrict__ outHi,
            float* __restrict__ Wcc, int* __restrict__ bcnt) {
  __shared__ float Wc2s[DIM_H][2];
  constexpr int CH = DIM_IN / 32;   // 8
  if (blockIdx.x == 17) {
    for (int i = threadIdx.x; i < NBKT * CPAD; i += 256) bcnt[i] = 0;
    return;
  }
  if (blockIdx.x == 16) {
    const int t = threadIdx.x;
    const int i = t >> 1, j = t & 1;
    float s = 0.f;
#pragma unroll 4
    for (int m = 0; m < DIM_H; ++m) s += W2[(size_t)i * DIM_H + m] * Wh[m * 2 + j];
    Wc2s[i][j] = s;
    __syncthreads();
    float c = 0.f;
#pragma unroll 4
    for (int k = 0; k < DIM_H; ++k) c += W1[(size_t)i * DIM_H + k] * Wc2s[k][j];
    Wcc[i * 2 + j] = c;
    if (t < 2) {
      float a = 0.f, b = 0.f;
      for (int k = 0; k < DIM_H; ++k) {
        a += b1[k] * Wc2s[k][t];
        b += b2[k] * Wh[k * 2 + t];
      }
      Wcc[256 + t] = a;           // c1
      Wcc[258 + t] = b + bh[t];   // bc
    }
    return;
  }
  int idx = blockIdx.x * 256 + threadIdx.x;   // < CH*512 = 4096
  int n  = idx & 15;
  int qq = (idx >> 4) & 3;
  int nt = (idx >> 6) & 7;
  int c  = idx >> 9;
  int col = nt * 16 + n;
  short8 h8, l8;
#pragma unroll
  for (int j = 0; j < 8; ++j) {
    float v = Wi[(size_t)(c * 32 + qq * 8 + j) * DIM_H + col];
    ushort hb = f2bf(v);
    ushort lb = f2bf(v - bf2f(hb));
    h8[j] = (short)hb;
    l8[j] = (short)lb;
  }
  ((short8*)outHi)[idx] = h8;
  ((short8*)outHi)[CH * 512 + idx] = l8;
}

// ---------------- single-pass bucket binning (no pre-scan, no 2nd edge read)
// record = src | (d&127)<<17; bucket chunk reserved via one global atomic per
// (block,bucket); records land at ebuf[bkt*CAP + pos], order-free per bucket.
__global__ __launch_bounds__(1024)
void k_bin1(const int* __restrict__ eidx, int* __restrict__ bcnt,
            unsigned* __restrict__ ebuf) {
  __shared__ int hist[NBKT];
  __shared__ int curL[NBKT];
  __shared__ int s_or;
  const int t = threadIdx.x;
  // per-block width detect: int64 input => all high words zero
  if (t == 0) s_or = 0;
  for (int i = t; i < NBKT; i += 1024) hist[i] = 0;
  __syncthreads();
  if (eidx[2 * t + 1] != 0) atomicOr(&s_or, 1);
  __syncthreads();
  const int is64 = (s_or == 0);

  unsigned rec[EPB / 1024];
  int bkt[EPB / 1024];
#pragma unroll
  for (int j = 0; j < EPB / 1024; ++j) {
    int e = blockIdx.x * EPB + j * 1024 + t;
    bkt[j] = -1;
    rec[j] = 0;
    if (e < N_EDGES) {
      unsigned s = (unsigned)get_src(eidx, is64, e);
      unsigned d = (unsigned)get_dst(eidx, is64, e);
      if (s < N_NODES && d < N_NODES) {
        bkt[j] = (int)(d >> 7);
        rec[j] = s | ((d & 127u) << 17);
        atomicAdd(&hist[bkt[j]], 1);
      }
    }
  }
  __syncthreads();
  for (int i = t; i < NBKT; i += 1024) {
    int h = hist[i];
    curL[i] = h ? atomicAdd(&bcnt[i * CPAD], h) : 0;
  }
  __syncthreads();
#pragma unroll
  for (int j = 0; j < EPB / 1024; ++j) {
    if (bkt[j] >= 0) {
      int pos = atomicAdd(&curL[bkt[j]], 1);
      ebuf[(size_t)bkt[j] * CAP + pos] = rec[j];
    }
  }
}

// ---------------- per-bucket degree -> dinv (sequential ebuf read) --------
__global__ __launch_bounds__(256)
void k_dinvB(const int* __restrict__ bcnt, const unsigned* __restrict__ ebuf,
             float* __restrict__ dinv) {
  __shared__ int hist[128];
  const int b = blockIdx.x, t = threadIdx.x;
  if (t < 128) hist[t] = 0;
  __syncthreads();
  const int cnt = bcnt[b * CPAD];
  const unsigned* eb = ebuf + (size_t)b * CAP;
  for (int i = t; i < cnt; i += 256) atomicAdd(&hist[eb[i] >> 17], 1);
  __syncthreads();
  if (t < 128) {
    int node = (b << 7) + t;
    if (node < N_NODES) dinv[node] = rsqrtf(1.0f + (float)hist[t]);
  }
}

// ------------- Cooperative MFMA GEMM, 64-row tile, double-buffered LDS with
// XOR-swizzled staging, ONE barrier per K-step, DEPTH-2 A prefetch (the load
// for step c+2 is issued while computing step c; step c+1's data — loaded a
// full phase earlier — is converted+written after the MFMAs). B prefetch
// stays depth-1 (L1/L2-resident). Fused z = relu(.)@Wcc epilogue.
// Emits tbl[row] = (dinv*z0, dinv*z1, dinv, 0).
template <int K>
__global__ __launch_bounds__(256, 4)
void k_gemm_xz(const float* __restrict__ A, const ushort* __restrict__ Bfrag,
               const float* __restrict__ bias, const float* __restrict__ Wcc,
               const float* __restrict__ dinv, float4* __restrict__ tbl) {
  constexpr int CH = K / 32;   // 8
  __shared__ __align__(16) ushort AhiS[2][256 * 8];
  __shared__ __align__(16) ushort AloS[2][256 * 8];
  const int tid = threadIdx.x;
  const int m0 = blockIdx.x * 64;
  const int wave = tid >> 6, lane = tid & 63;
  const int m_l = lane & 15, quad = lane >> 4;
  const int rs = tid >> 2, q = tid & 3;

  f32x4 acc[2][4];
#pragma unroll
  for (int i = 0; i < 2; ++i)
#pragma unroll
    for (int j = 0; j < 4; ++j) acc[i][j] = (f32x4){0.f, 0.f, 0.f, 0.f};

  const short8* Bhi8 = (const short8*)Bfrag;
  const short8* Blo8 = Bhi8 + CH * 512;
  short8* Ah = (short8*)AhiS;
  short8* Al = (short8*)AloS;

  const int gr = m0 + rs;
  const float* Ap = &A[(size_t)((gr < N_NODES) ? gr : (N_NODES - 1)) * K + q * 8];
  const int went = (rs >> 4) * 64 + q * 16 + ((rs & 15) ^ (q << 2));   // swizzled write
  const int rent = quad * 16 + (m_l ^ (quad << 2));                     // + mt*64 on read

  // prologue: stage c=0 into buf 0; va = c=1 data in flight; preload B c=0
  float va[8];
  {
    float v0[8];
    load8(Ap, v0);
    load8(Ap + 32, va);
    short8 h, l;
    cvt_split(v0, h, l);
    Ah[went] = h;
    Al[went] = l;
  }
  const int bq = quad * 16 + m_l;
  short8 bh0 = Bhi8[(wave * 2 + 0) * 64 + bq];
  short8 bl0 = Blo8[(wave * 2 + 0) * 64 + bq];
  short8 bh1 = Bhi8[(wave * 2 + 1) * 64 + bq];
  short8 bl1 = Blo8[(wave * 2 + 1) * 64 + bq];
  __syncthreads();

#pragma unroll
  for (int c = 0; c < CH; ++c) {
    const int cur = c & 1, nxt = cur ^ 1;
    // depth-2: issue the A load for step c+2 (consumed next step, read from
    // LDS the step after) — ~2 MFMA phases of latency budget
    float vb[8];
    if (c + 2 < CH) load8(Ap + (c + 2) * 32, vb);
    // depth-1 B prefetch for step c+1
    short8 nbh0, nbl0, nbh1, nbl1;
    if (c + 1 < CH) {
      const int b0 = ((c + 1) * 8 + wave * 2 + 0) * 64 + bq;
      const int b1 = ((c + 1) * 8 + wave * 2 + 1) * 64 + bq;
      nbh0 = Bhi8[b0]; nbl0 = Blo8[b0];
      nbh1 = Bhi8[b1]; nbl1 = Blo8[b1];
    }
    const short8* AhC = Ah + cur * 256;
    const short8* AlC = Al + cur * 256;
#pragma unroll
    for (int mt = 0; mt < 4; ++mt) {
      short8 ahi = AhC[mt * 64 + rent];
      short8 alo = AlC[mt * 64 + rent];
      acc[0][mt] = __builtin_amdgcn_mfma_f32_16x16x32_bf16(ahi, bh0, acc[0][mt], 0, 0, 0);
      acc[0][mt] = __builtin_amdgcn_mfma_f32_16x16x32_bf16(ahi, bl0, acc[0][mt], 0, 0, 0);
      acc[0][mt] = __builtin_amdgcn_mfma_f32_16x16x32_bf16(alo, bh0, acc[0][mt], 0, 0, 0);
      acc[1][mt] = __builtin_amdgcn_mfma_f32_16x16x32_bf16(ahi, bh1, acc[1][mt], 0, 0, 0);
      acc[1][mt] = __builtin_amdgcn_mfma_f32_16x16x32_bf16(ahi, bl1, acc[1][mt], 0, 0, 0);
      acc[1][mt] = __builtin_amdgcn_mfma_f32_16x16x32_bf16(alo, bh1, acc[1][mt], 0, 0, 0);
    }
    // convert + write step c+1's data (landed a full phase ago) to other buf
    if (c + 1 < CH) {
      short8 h, l;
      cvt_split(va, h, l);
      Ah[nxt * 256 + went] = h;
      Al[nxt * 256 + went] = l;
      if (c + 2 < CH) {
#pragma unroll
        for (int j = 0; j < 8; ++j) va[j] = vb[j];
      }
      bh0 = nbh0; bl0 = nbl0; bh1 = nbh1; bl1 = nbl1;
    }
    __syncthreads();
  }

  // ---- fused epilogue: p = relu(acc + bias) @ Wcc, reduced over 128 cols
  float p0[4][4], p1[4][4];
#pragma unroll
  for (int mt = 0; mt < 4; ++mt)
#pragma unroll
    for (int r = 0; r < 4; ++r) { p0[mt][r] = 0.f; p1[mt][r] = 0.f; }
#pragma unroll
  for (int ntl = 0; ntl < 2; ++ntl) {
    const int colg = (wave * 2 + ntl) * 16 + m_l;
    const float bv = bias[colg];
    const float w0 = Wcc[colg * 2 + 0];
    const float w1 = Wcc[colg * 2 + 1];
#pragma unroll
    for (int mt = 0; mt < 4; ++mt)
#pragma unroll
      for (int r = 0; r < 4; ++r) {
        float hv = fmaxf(acc[ntl][mt][r] + bv, 0.f);   // relu(h1)
        p0[mt][r] += hv * w0;
        p1[mt][r] += hv * w1;
      }
  }
#pragma unroll
  for (int o = 1; o < 16; o <<= 1) {
#pragma unroll
    for (int mt = 0; mt < 4; ++mt)
#pragma unroll
      for (int r = 0; r < 4; ++r) {
        p0[mt][r] += __shfl_xor(p0[mt][r], o);
        p1[mt][r] += __shfl_xor(p1[mt][r], o);
      }
  }
  // cross-wave reduction via LDS (staging dead after final barrier above)
  float* zred = (float*)AhiS;   // [j][wave][quad][mt][r] = [2][4][4][4][4]
  if (m_l == 0) {
#pragma unroll
    for (int mt = 0; mt < 4; ++mt)
#pragma unroll
      for (int r = 0; r < 4; ++r) {
        zred[(((0 * 4 + wave) * 4 + quad) * 4 + mt) * 4 + r] = p0[mt][r];
        zred[(((1 * 4 + wave) * 4 + quad) * 4 + mt) * 4 + r] = p1[mt][r];
      }
  }
  __syncthreads();
  if (tid < 64) {
    const int mt = tid >> 4, qd = (tid >> 2) & 3, r = tid & 3;
    const int rowg = m0 + tid;
    if (rowg < N_NODES) {
      float s0 = 0.f, s1 = 0.f;
#pragma unroll
      for (int w = 0; w < 4; ++w) {
        s0 += zred[(((0 * 4 + w) * 4 + qd) * 4 + mt) * 4 + r];
        s1 += zred[(((1 * 4 + w) * 4 + qd) * 4 + mt) * 4 + r];
      }
      float dn = dinv[rowg];
      tbl[rowg] = make_float4(dn * s0, dn * s1, dn, 0.f);
    }
  }
}

// ---------------- pass 1, bucket-centric: LDS accumulate 3 floats/edge.
// yt[d] = dinv²·(z[d]+Σz[s]); g[d] = dinv·(dinv+Σdinv[s]).
__global__ __launch_bounds__(256)
void k_aggr1B(const int* __restrict__ bcnt, const unsigned* __restrict__ ebuf,
              const float4* __restrict__ tbl, float2* __restrict__ tb2,
              float* __restrict__ g) {
  __shared__ float acc[128][4];
  const int b = blockIdx.x, t = threadIdx.x;
  if (t < 128) { acc[t][0] = 0.f; acc[t][1] = 0.f; acc[t][2] = 0.f; }
  __syncthreads();
  const int cnt = bcnt[b * CPAD];
  const unsigned* eb = ebuf + (size_t)b * CAP;
  for (int i = t; i < cnt; i += 256) {
    unsigned r = eb[i];
    float4 v = tbl[r & 0x1FFFFu];
    int d = r >> 17;
    atomicAdd(&acc[d][0], v.x);
    atomicAdd(&acc[d][1], v.y);
    atomicAdd(&acc[d][2], v.z);
  }
  __syncthreads();
  if (t < 128) {
    int node = (b << 7) + t;
    if (node < N_NODES) {
      float4 self = tbl[node];
      float dn = self.z;
      tb2[node] = make_float2(dn * dn * (acc[t][0] + self.x),
                              dn * dn * (acc[t][1] + self.y));
      g[node] = dn * (acc[t][2] + self.z);
    }
  }
}

// ---------------- pass 2, bucket-centric: out = bc + dinv·(yt+Σyt) + g·c1.
// tail = {c1[0],c1[1],bc[0],bc[1]}
__global__ __launch_bounds__(256)
void k_aggr2B(const int* __restrict__ bcnt, const unsigned* __restrict__ ebuf,
              const float2* __restrict__ tb2, const float4* __restrict__ tbl,
              const float* __restrict__ g, const float* __restrict__ tail,
              float* __restrict__ out) {
  __shared__ float acc[128][2];
  const int b = blockIdx.x, t = threadIdx.x;
  if (t < 128) { acc[t][0] = 0.f; acc[t][1] = 0.f; }
  __syncthreads();
  const int cnt = bcnt[b * CPAD];
  const unsigned* eb = ebuf + (size_t)b * CAP;
  for (int i = t; i < cnt; i += 256) {
    unsigned r = eb[i];
    float2 v = tb2[r & 0x1FFFFu];
    int d = r >> 17;
    atomicAdd(&acc[d][0], v.x);
    atomicAdd(&acc[d][1], v.y);
  }
  __syncthreads();
  if (t < 128) {
    int node = (b << 7) + t;
    if (node < N_NODES) {
      float2 self = tb2[node];
      float dn = tbl[node].z;
      float gv = g[node];
      float o0 = dn * (acc[t][0] + self.x) + gv * tail[0] + tail[2];
      float o1 = dn * (acc[t][1] + self.y) + gv * tail[1] + tail[3];
      reinterpret_cast<float2*>(out)[node] = make_float2(o0, o1);
    }
  }
}

// --------------------------------------------- fp32 fallback (small ws) ----
__global__ __launch_bounds__(1024) void k_detect(const int* __restrict__ e,
                                                 int* __restrict__ flag) {
  __shared__ int s;
  if (threadIdx.x == 0) s = 0;
  __syncthreads();
  atomicOr(&s, e[2 * threadIdx.x + 1]);
  __syncthreads();
  if (threadIdx.x == 0) *flag = (s == 0) ? 1 : 0;
}

__global__ __launch_bounds__(256) void k_zero(int* __restrict__ p, int n) {
  int i = blockIdx.x * 256 + threadIdx.x;
  if (i < n) p[i] = 0;
}

__global__ __launch_bounds__(256) void k_count(const int* __restrict__ eidx,
                                               const int* __restrict__ flag,
                                               int* __restrict__ off) {
  int e = blockIdx.x * 256 + threadIdx.x;
  int is64 = *flag;
  if (e < N_EDGES) {
    unsigned d = (unsigned)get_dst(eidx, is64, e);
    if (d < N_NODES) atomicAdd(&off[d], 1);
  }
}

__global__ __launch_bounds__(256) void k_dinv_old(const int* __restrict__ off,
                                                  float* __restrict__ dinv) {
  int i = blockIdx.x * 256 + threadIdx.x;
  if (i < N_NODES) dinv[i] = rsqrtf(1.0f + (float)off[i]);
}

template <int K>
__global__ __launch_bounds__(256)
void k_gemm(const float* __restrict__ A, const float* __restrict__ B,
            const float* __restrict__ bias, const float* __restrict__ scale,
            float* __restrict__ C, const int do_relu) {
  __shared__ float As[64][33];
  const int tid = threadIdx.x;
  const int tx = tid & 15;
  const int ty = tid >> 4;
  const int m0 = blockIdx.x * 64;

  float acc[4][8];
#pragma unroll
  for (int i = 0; i < 4; ++i)
#pragma unroll
    for (int j = 0; j < 8; ++j) acc[i][j] = 0.f;

  const int rs = tid >> 2;
  const int ks = (tid & 3) * 8;

  for (int k0 = 0; k0 < K; k0 += 32) {
    float av8[8];
    const int gm = m0 + rs;
    if (gm < N_NODES) {
      load8(&A[(size_t)gm * K + k0 + ks], av8);
    } else {
#pragma unroll
      for (int j = 0; j < 8; ++j) av8[j] = 0.f;
    }
    __syncthreads();
#pragma unroll
    for (int j = 0; j < 8; ++j) As[rs][ks + j] = av8[j];
    __syncthreads();

    const float* Bp = B + (size_t)k0 * DIM_H + tx * 8;
#pragma unroll 4
    for (int k = 0; k < 32; ++k) {
      float bv[8];
      load8(Bp + (size_t)k * DIM_H, bv);
      float av[4];
#pragma unroll
      for (int rr = 0; rr < 4; ++rr) av[rr] = As[ty * 4 + rr][k];
#pragma unroll
      for (int rr = 0; rr < 4; ++rr)
#pragma unroll
        for (int cc = 0; cc < 8; ++cc)
          acc[rr][cc] = fmaf(av[rr], bv[cc], acc[rr][cc]);
    }
  }

  float bs[8];
  if (bias) {
    load8(bias + tx * 8, bs);
  } else {
#pragma unroll
    for (int j = 0; j < 8; ++j) bs[j] = 0.f;
  }
#pragma unroll
  for (int rr = 0; rr < 4; ++rr) {
    const int gm = m0 + ty * 4 + rr;
    if (gm < N_NODES) {
      float sc = scale ? scale[gm] : 1.0f;
      float v[8];
#pragma unroll
      for (int cc = 0; cc < 8; ++cc) {
        float t = acc[rr][cc] + bs[cc];
        if (do_relu) t = fmaxf(t, 0.f);
        v[cc] = t * sc;
      }
      float* Cp = &C[(size_t)gm * DIM_H + tx * 8];
      reinterpret_cast<float4*>(Cp)[0] = make_float4(v[0], v[1], v[2], v[3]);
      reinterpret_cast<float4*>(Cp)[1] = make_float4(v[4], v[5], v[6], v[7]);
    }
  }
}

__global__ __launch_bounds__(256)
void k_aggr_init(const float* __restrict__ t, const float* __restrict__ dinv,
                 const float* __restrict__ bias, float* __restrict__ h) {
  int idx = blockIdx.x * 256 + threadIdx.x;
  if (idx < N_NODES * DIM_H) {
    int i = idx >> 7;
    int c = idx & 127;
    float d = dinv[i];
    h[idx] = bias[c] + t[idx] * d * d;
  }
}

__global__ __launch_bounds__(256)
void k_aggr_edges(const int* __restrict__ eidx, const int* __restrict__ flag,
                  const float* __restrict__ t, const float* __restrict__ dinv,
                  float* __restrict__ h) {
  int e = blockIdx.x * 2 + (threadIdx.x >> 7);
  int c = threadIdx.x & 127;
  int is64 = *flag;
  if (e < N_EDGES) {
    unsigned s = (unsigned)get_src(eidx, is64, e);
    unsigned d = (unsigned)get_dst(eidx, is64, e);
    if (s < N_NODES && d < N_NODES) {
      float nrm = dinv[s] * dinv[d];
      unsafeAtomicAdd(&h[(size_t)d * DIM_H + c], t[(size_t)s * DIM_H + c] * nrm);
    }
  }
}

__global__ __launch_bounds__(256)
void k_head_f32(const float* __restrict__ h, const float* __restrict__ Wh,
                const float* __restrict__ bh, float* __restrict__ out) {
  int node = blockIdx.x * 4 + (threadIdx.x >> 6);
  int lane = threadIdx.x & 63;
  if (node >= N_NODES) return;
  float h0 = h[(size_t)node * DIM_H + lane];
  float h1 = h[(size_t)node * DIM_H + 64 + lane];
  float s0 = h0 * Wh[lane * 2 + 0] + h1 * Wh[(lane + 64) * 2 + 0];
  float s1 = h0 * Wh[lane * 2 + 1] + h1 * Wh[(lane + 64) * 2 + 1];
#pragma unroll
  for (int off = 32; off > 0; off >>= 1) {
    s0 += __shfl_down(s0, off);
    s1 += __shfl_down(s1, off);
  }
  if (lane == 0) {
    reinterpret_cast<float2*>(out)[node] = make_float2(s0 + bh[0], s1 + bh[1]);
  }
}

// ---------------------------------------------------------------- launch
extern "C" void kernel_launch(void* const* d_in, const int* in_sizes, int n_in,
                              void* d_out, int out_size, void* d_ws, size_t ws_size,
                              hipStream_t stream) {
  (void)in_sizes; (void)n_in; (void)out_size;
  const int* eidx = (const int*)d_in[0];
  const float* x  = (const float*)d_in[1];
  const float* Wi = (const float*)d_in[2];
  const float* bi = (const float*)d_in[3];
  const float* W1 = (const float*)d_in[4];
  const float* b1 = (const float*)d_in[5];
  const float* W2 = (const float*)d_in[6];
  const float* b2 = (const float*)d_in[7];
  const float* Wh = (const float*)d_in[8];
  const float* bh = (const float*)d_in[9];
  float* out = (float*)d_out;

  const int gE  = (N_EDGES + 255) / 256;
  const int gM  = (N_NODES + 63) / 64;       // 1563
  const int gW  = (N_NODES + 3) / 4;

  char* ws = (char*)d_ws;

  const size_t need1 = 16201600;

  if (ws_size >= need1) {
    float*    Wcc  = (float*)(ws + 4096);       // 260 floats
    ushort*   bfWi = (ushort*)(ws + 8192);      // 131072 B -> 139264
    int*      bcnt = (int*)(ws + 139264);       // 50048 B  -> 189312
    float*    dinv = (float*)(ws + 189312);     // 400000 B -> 589312
    float4*   tbl  = (float4*)(ws + 589312);    // 1600000 B -> 2189312
    float2*   tb2  = (float2*)(ws + 2189312);   // 800000 B -> 2989312
    float*    g    = (float*)(ws + 2989312);    // 400000 B -> 3389312
    unsigned* ebuf = (unsigned*)(ws + 3389312); // 12812288 B -> 16201600

    // weight prep (+bcnt zero, block 17) — no deps, first
    k_prep<<<18, 256, 0, stream>>>(Wi, W1, W2, Wh, b1, b2, bh, bfWi, Wcc, bcnt);
    // single-pass bucket binning: ONE edge-list read, no scan, no csr
    k_bin1<<<NBLK, 1024, 0, stream>>>(eidx, bcnt, ebuf);
    // per-bucket degree -> dinv
    k_dinvB<<<NBKT, 256, 0, stream>>>(bcnt, ebuf, dinv);
    // z = relu(x@Wi+bi) @ Wcc fused into GEMM epilogue -> tbl (N x float4)
    k_gemm_xz<DIM_IN><<<gM, 256, 0, stream>>>(x, bfWi, bi, Wcc, dinv, tbl);
    // bucket-centric aggregations: LDS atomics, L2-resident gathers
    k_aggr1B<<<NBKT, 256, 0, stream>>>(bcnt, ebuf, tbl, tb2, g);
    k_aggr2B<<<NBKT, 256, 0, stream>>>(bcnt, ebuf, tb2, tbl, g, Wcc + 256, out);
  } else {
    // fallback: fp32 atomic-scatter path (~103 MB)
    const int gN  = (N_NODES + 255) / 256;
    int*   flag = (int*)ws;
    int*   off  = (int*)(ws + 4096);
    float* dinv = (float*)(ws + 404480);
    float* fbA  = (float*)(ws + 804864);
    float* fbB  = (float*)(ws + 804864 + (size_t)N_NODES * DIM_H * 4);
    const int gNH = (N_NODES * DIM_H + 255) / 256;
    const int gE2 = (N_EDGES + 1) / 2;
    k_detect<<<1, 1024, 0, stream>>>(eidx, flag);
    k_zero<<<gN, 256, 0, stream>>>(off, N_NODES);
    k_count<<<gE, 256, 0, stream>>>(eidx, flag, off);
    k_dinv_old<<<gN, 256, 0, stream>>>(off, dinv);

    k_gemm<DIM_IN><<<gM, 256, 0, stream>>>(x, Wi, bi, nullptr, fbA, 1);
    k_gemm<DIM_H><<<gM, 256, 0, stream>>>(fbA, W1, nullptr, nullptr, fbB, 0);
    k_aggr_init<<<gNH, 256, 0, stream>>>(fbB, dinv, b1, fbA);
    k_aggr_edges<<<gE2, 256, 0, stream>>>(eidx, flag, fbB, dinv, fbA);
    k_gemm<DIM_H><<<gM, 256, 0, stream>>>(fbA, W2, nullptr, nullptr, fbB, 0);
    k_aggr_init<<<gNH, 256, 0, stream>>>(fbB, dinv, b2, fbA);
    k_aggr_edges<<<gE2, 256, 0, stream>>>(eidx, flag, fbB, dinv, fbA);
    k_head_f32<<<gW, 256, 0, stream>>>(fbA, Wh, bh, out);
  }
}

// Round 12
// 282.264 us; speedup vs baseline: 1.1309x; 1.0125x over previous
//
#include <hip/hip_runtime.h>
#include <hip/hip_bf16.h>

#define N_NODES 100000
#define N_EDGES 1600000
#define DIM_IN  256
#define DIM_H   128

#define NBKT 782          // ceil(N_NODES / 128) buckets of 128 nodes
#define CPAD 16           // ints per padded counter (one cacheline)
#define CAP  4096         // records per bucket (mean 2048, sd ~45 -> safe)
#define EPB  8192         // edges per build block
#define NBLK ((N_EDGES + EPB - 1) / EPB)   // 196

typedef __attribute__((ext_vector_type(8))) short short8;
typedef __attribute__((ext_vector_type(4))) float f32x4;

__device__ __forceinline__ int get_src(const int* e, int is64, int i) {
  return is64 ? e[2 * i] : e[i];
}
__device__ __forceinline__ int get_dst(const int* e, int is64, int i) {
  return is64 ? e[2 * (N_EDGES + i)] : e[N_EDGES + i];
}

// ---------------------------------------------------------------- bf16 utils
__device__ __forceinline__ ushort f2bf(float f) {
  unsigned u = __float_as_uint(f);
  unsigned r = (u + 0x7fffu + ((u >> 16) & 1u)) >> 16;
  return (ushort)r;
}
__device__ __forceinline__ float bf2f(ushort h) {
  return __uint_as_float(((unsigned)h) << 16);
}

__device__ __forceinline__ void load8(const float* p, float* o) {
  float4 a = reinterpret_cast<const float4*>(p)[0];
  float4 b = reinterpret_cast<const float4*>(p)[1];
  o[0] = a.x; o[1] = a.y; o[2] = a.z; o[3] = a.w;
  o[4] = b.x; o[5] = b.y; o[6] = b.z; o[7] = b.w;
}

__device__ __forceinline__ void cvt_split(const float* v, short8& h, short8& l) {
#pragma unroll
  for (int j = 0; j < 8; ++j) {
    ushort hb = f2bf(v[j]);
    ushort lb = f2bf(v[j] - bf2f(hb));
    h[j] = (short)hb;
    l[j] = (short)lb;
  }
}

// Blocks 0..15: split Wi[256x128] into MFMA B-fragment planes (hi, lo).
// Block 16: collapsed tail weights Wcc = W1@(W2@Wh), c1 = b1@(W2@Wh),
//           bc = b2@Wh + bh  (stored Wcc[0..255], [256..257], [258..259]).
// Block 17: zero the bucket counters.
__global__ __launch_bounds__(256)
void k_prep(const float* __restrict__ Wi, const float* __restrict__ W1,
            const float* __restrict__ W2, const float* __restrict__ Wh,
            const float* __restrict__ b1, const float* __restrict__ b2,
            const float* __restrict__ bh, ushort* __restrict__ outHi,
            float* __restrict__ Wcc, int* __restrict__ bcnt) {
  __shared__ float Wc2s[DIM_H][2];
  constexpr int CH = DIM_IN / 32;   // 8
  if (blockIdx.x == 17) {
    for (int i = threadIdx.x; i < NBKT * CPAD; i += 256) bcnt[i] = 0;
    return;
  }
  if (blockIdx.x == 16) {
    const int t = threadIdx.x;
    const int i = t >> 1, j = t & 1;
    float s = 0.f;
#pragma unroll 4
    for (int m = 0; m < DIM_H; ++m) s += W2[(size_t)i * DIM_H + m] * Wh[m * 2 + j];
    Wc2s[i][j] = s;
    __syncthreads();
    float c = 0.f;
#pragma unroll 4
    for (int k = 0; k < DIM_H; ++k) c += W1[(size_t)i * DIM_H + k] * Wc2s[k][j];
    Wcc[i * 2 + j] = c;
    if (t < 2) {
      float a = 0.f, b = 0.f;
      for (int k = 0; k < DIM_H; ++k) {
        a += b1[k] * Wc2s[k][t];
        b += b2[k] * Wh[k * 2 + t];
      }
      Wcc[256 + t] = a;           // c1
      Wcc[258 + t] = b + bh[t];   // bc
    }
    return;
  }
  int idx = blockIdx.x * 256 + threadIdx.x;   // < CH*512 = 4096
  int n  = idx & 15;
  int qq = (idx >> 4) & 3;
  int nt = (idx >> 6) & 7;
  int c  = idx >> 9;
  int col = nt * 16 + n;
  short8 h8, l8;
#pragma unroll
  for (int j = 0; j < 8; ++j) {
    float v = Wi[(size_t)(c * 32 + qq * 8 + j) * DIM_H + col];
    ushort hb = f2bf(v);
    ushort lb = f2bf(v - bf2f(hb));
    h8[j] = (short)hb;
    l8[j] = (short)lb;
  }
  ((short8*)outHi)[idx] = h8;
  ((short8*)outHi)[CH * 512 + idx] = l8;
}

// ---------------- single-pass bucket binning with BLOCK-LOCAL COUNTING SORT.
// record = src | (d&127)<<17. Per block: histogram -> LDS prefix scan ->
// scatter records into sorted LDS array -> linear write-out. Consecutive LDS
// positions map to consecutive global positions within each bucket's chunk
// (mean run ~10.5 records), so global writes are piecewise-coalesced instead
// of 1 line per 4B record (~5x write-amplification kill).
__global__ __launch_bounds__(1024)
void k_bin1(const int* __restrict__ eidx, int* __restrict__ bcnt,
            unsigned* __restrict__ ebuf) {
  __shared__ int hist[NBKT];        // counts, then lofs (exclusive base)
  __shared__ int gbase[NBKT];       // global chunk base per bucket
  __shared__ int lcur[NBKT];        // local fill cursor
  __shared__ int sm[1024];          // scan scratch
  __shared__ unsigned srt[EPB];     // 32 KB sorted records
  __shared__ ushort  sbk[EPB];      // 16 KB bucket id per sorted slot
  __shared__ int s_or;
  const int t = threadIdx.x;
  // per-block width detect: int64 input => all high words zero
  if (t == 0) s_or = 0;
  for (int i = t; i < NBKT; i += 1024) hist[i] = 0;
  __syncthreads();
  if (eidx[2 * t + 1] != 0) atomicOr(&s_or, 1);
  __syncthreads();
  const int is64 = (s_or == 0);

  unsigned rec[EPB / 1024];
  int bkt[EPB / 1024];
#pragma unroll
  for (int j = 0; j < EPB / 1024; ++j) {
    int e = blockIdx.x * EPB + j * 1024 + t;
    bkt[j] = -1;
    rec[j] = 0;
    if (e < N_EDGES) {
      unsigned s = (unsigned)get_src(eidx, is64, e);
      unsigned d = (unsigned)get_dst(eidx, is64, e);
      if (s < N_NODES && d < N_NODES) {
        bkt[j] = (int)(d >> 7);
        rec[j] = s | ((d & 127u) << 17);
        atomicAdd(&hist[bkt[j]], 1);
      }
    }
  }
  __syncthreads();
  // 1024-wide inclusive scan of hist (buckets t >= NBKT contribute 0)
  const int v = (t < NBKT) ? hist[t] : 0;
  sm[t] = v;
  __syncthreads();
  for (int d = 1; d < 1024; d <<= 1) {
    int u = (t >= d) ? sm[t - d] : 0;
    __syncthreads();
    sm[t] += u;
    __syncthreads();
  }
  if (t < NBKT) {
    const int excl = sm[t] - v;
    gbase[t] = v ? atomicAdd(&bcnt[t * CPAD], v) : 0;  // reserve global chunk
    hist[t] = excl;                                     // lofs
    lcur[t] = excl;                                     // fill cursor
  }
  __syncthreads();
  // scatter into sorted LDS array
#pragma unroll
  for (int j = 0; j < EPB / 1024; ++j) {
    if (bkt[j] >= 0) {
      int p = atomicAdd(&lcur[bkt[j]], 1);
      srt[p] = rec[j];
      sbk[p] = (ushort)bkt[j];
    }
  }
  __syncthreads();
  // piecewise-coalesced write-out
  const int total = sm[1023];
  for (int i = t; i < total; i += 1024) {
    const int b = sbk[i];
    ebuf[(size_t)b * CAP + gbase[b] + (i - hist[b])] = srt[i];
  }
}

// ---------------- per-bucket degree -> dinv (sequential ebuf read) --------
__global__ __launch_bounds__(256)
void k_dinvB(const int* __restrict__ bcnt, const unsigned* __restrict__ ebuf,
             float* __restrict__ dinv) {
  __shared__ int hist[128];
  const int b = blockIdx.x, t = threadIdx.x;
  if (t < 128) hist[t] = 0;
  __syncthreads();
  const int cnt = bcnt[b * CPAD];
  const unsigned* eb = ebuf + (size_t)b * CAP;
  for (int i = t; i < cnt; i += 256) atomicAdd(&hist[eb[i] >> 17], 1);
  __syncthreads();
  if (t < 128) {
    int node = (b << 7) + t;
    if (node < N_NODES) dinv[node] = rsqrtf(1.0f + (float)hist[t]);
  }
}

// ------------- Cooperative MFMA GEMM, 64-row tile, double-buffered LDS with
// XOR-swizzled staging, ONE barrier per K-step, DEPTH-2 A prefetch (the load
// for step c+2 is issued while computing step c; step c+1's data — loaded a
// full phase earlier — is converted+written after the MFMAs). B prefetch
// stays depth-1 (L1/L2-resident). Fused z = relu(.)@Wcc epilogue.
// Emits tbl[row] = (dinv*z0, dinv*z1, dinv, 0).
template <int K>
__global__ __launch_bounds__(256, 4)
void k_gemm_xz(const float* __restrict__ A, const ushort* __restrict__ Bfrag,
               const float* __restrict__ bias, const float* __restrict__ Wcc,
               const float* __restrict__ dinv, float4* __restrict__ tbl) {
  constexpr int CH = K / 32;   // 8
  __shared__ __align__(16) ushort AhiS[2][256 * 8];
  __shared__ __align__(16) ushort AloS[2][256 * 8];
  const int tid = threadIdx.x;
  const int m0 = blockIdx.x * 64;
  const int wave = tid >> 6, lane = tid & 63;
  const int m_l = lane & 15, quad = lane >> 4;
  const int rs = tid >> 2, q = tid & 3;

  f32x4 acc[2][4];
#pragma unroll
  for (int i = 0; i < 2; ++i)
#pragma unroll
    for (int j = 0; j < 4; ++j) acc[i][j] = (f32x4){0.f, 0.f, 0.f, 0.f};

  const short8* Bhi8 = (const short8*)Bfrag;
  const short8* Blo8 = Bhi8 + CH * 512;
  short8* Ah = (short8*)AhiS;
  short8* Al = (short8*)AloS;

  const int gr = m0 + rs;
  const float* Ap = &A[(size_t)((gr < N_NODES) ? gr : (N_NODES - 1)) * K + q * 8];
  const int went = (rs >> 4) * 64 + q * 16 + ((rs & 15) ^ (q << 2));   // swizzled write
  const int rent = quad * 16 + (m_l ^ (quad << 2));                     // + mt*64 on read

  // prologue: stage c=0 into buf 0; va = c=1 data in flight; preload B c=0
  float va[8];
  {
    float v0[8];
    load8(Ap, v0);
    load8(Ap + 32, va);
    short8 h, l;
    cvt_split(v0, h, l);
    Ah[went] = h;
    Al[went] = l;
  }
  const int bq = quad * 16 + m_l;
  short8 bh0 = Bhi8[(wave * 2 + 0) * 64 + bq];
  short8 bl0 = Blo8[(wave * 2 + 0) * 64 + bq];
  short8 bh1 = Bhi8[(wave * 2 + 1) * 64 + bq];
  short8 bl1 = Blo8[(wave * 2 + 1) * 64 + bq];
  __syncthreads();

#pragma unroll
  for (int c = 0; c < CH; ++c) {
    const int cur = c & 1, nxt = cur ^ 1;
    // depth-2: issue the A load for step c+2 (consumed next step, read from
    // LDS the step after) — ~2 MFMA phases of latency budget
    float vb[8];
    if (c + 2 < CH) load8(Ap + (c + 2) * 32, vb);
    // depth-1 B prefetch for step c+1
    short8 nbh0, nbl0, nbh1, nbl1;
    if (c + 1 < CH) {
      const int b0 = ((c + 1) * 8 + wave * 2 + 0) * 64 + bq;
      const int b1 = ((c + 1) * 8 + wave * 2 + 1) * 64 + bq;
      nbh0 = Bhi8[b0]; nbl0 = Blo8[b0];
      nbh1 = Bhi8[b1]; nbl1 = Blo8[b1];
    }
    const short8* AhC = Ah + cur * 256;
    const short8* AlC = Al + cur * 256;
#pragma unroll
    for (int mt = 0; mt < 4; ++mt) {
      short8 ahi = AhC[mt * 64 + rent];
      short8 alo = AlC[mt * 64 + rent];
      acc[0][mt] = __builtin_amdgcn_mfma_f32_16x16x32_bf16(ahi, bh0, acc[0][mt], 0, 0, 0);
      acc[0][mt] = __builtin_amdgcn_mfma_f32_16x16x32_bf16(ahi, bl0, acc[0][mt], 0, 0, 0);
      acc[0][mt] = __builtin_amdgcn_mfma_f32_16x16x32_bf16(alo, bh0, acc[0][mt], 0, 0, 0);
      acc[1][mt] = __builtin_amdgcn_mfma_f32_16x16x32_bf16(ahi, bh1, acc[1][mt], 0, 0, 0);
      acc[1][mt] = __builtin_amdgcn_mfma_f32_16x16x32_bf16(ahi, bl1, acc[1][mt], 0, 0, 0);
      acc[1][mt] = __builtin_amdgcn_mfma_f32_16x16x32_bf16(alo, bh1, acc[1][mt], 0, 0, 0);
    }
    // convert + write step c+1's data (landed a full phase ago) to other buf
    if (c + 1 < CH) {
      short8 h, l;
      cvt_split(va, h, l);
      Ah[nxt * 256 + went] = h;
      Al[nxt * 256 + went] = l;
      if (c + 2 < CH) {
#pragma unroll
        for (int j = 0; j < 8; ++j) va[j] = vb[j];
      }
      bh0 = nbh0; bl0 = nbl0; bh1 = nbh1; bl1 = nbl1;
    }
    __syncthreads();
  }

  // ---- fused epilogue: p = relu(acc + bias) @ Wcc, reduced over 128 cols
  float p0[4][4], p1[4][4];
#pragma unroll
  for (int mt = 0; mt < 4; ++mt)
#pragma unroll
    for (int r = 0; r < 4; ++r) { p0[mt][r] = 0.f; p1[mt][r] = 0.f; }
#pragma unroll
  for (int ntl = 0; ntl < 2; ++ntl) {
    const int colg = (wave * 2 + ntl) * 16 + m_l;
    const float bv = bias[colg];
    const float w0 = Wcc[colg * 2 + 0];
    const float w1 = Wcc[colg * 2 + 1];
#pragma unroll
    for (int mt = 0; mt < 4; ++mt)
#pragma unroll
      for (int r = 0; r < 4; ++r) {
        float hv = fmaxf(acc[ntl][mt][r] + bv, 0.f);   // relu(h1)
        p0[mt][r] += hv * w0;
        p1[mt][r] += hv * w1;
      }
  }
#pragma unroll
  for (int o = 1; o < 16; o <<= 1) {
#pragma unroll
    for (int mt = 0; mt < 4; ++mt)
#pragma unroll
      for (int r = 0; r < 4; ++r) {
        p0[mt][r] += __shfl_xor(p0[mt][r], o);
        p1[mt][r] += __shfl_xor(p1[mt][r], o);
      }
  }
  // cross-wave reduction via LDS (staging dead after final barrier above)
  float* zred = (float*)AhiS;   // [j][wave][quad][mt][r] = [2][4][4][4][4]
  if (m_l == 0) {
#pragma unroll
    for (int mt = 0; mt < 4; ++mt)
#pragma unroll
      for (int r = 0; r < 4; ++r) {
        zred[(((0 * 4 + wave) * 4 + quad) * 4 + mt) * 4 + r] = p0[mt][r];
        zred[(((1 * 4 + wave) * 4 + quad) * 4 + mt) * 4 + r] = p1[mt][r];
      }
  }
  __syncthreads();
  if (tid < 64) {
    const int mt = tid >> 4, qd = (tid >> 2) & 3, r = tid & 3;
    const int rowg = m0 + tid;
    if (rowg < N_NODES) {
      float s0 = 0.f, s1 = 0.f;
#pragma unroll
      for (int w = 0; w < 4; ++w) {
        s0 += zred[(((0 * 4 + w) * 4 + qd) * 4 + mt) * 4 + r];
        s1 += zred[(((1 * 4 + w) * 4 + qd) * 4 + mt) * 4 + r];
      }
      float dn = dinv[rowg];
      tbl[rowg] = make_float4(dn * s0, dn * s1, dn, 0.f);
    }
  }
}

// ---------------- pass 1, bucket-centric: LDS accumulate 3 floats/edge.
// yt[d] = dinv²·(z[d]+Σz[s]); g[d] = dinv·(dinv+Σdinv[s]).
__global__ __launch_bounds__(256)
void k_aggr1B(const int* __restrict__ bcnt, const unsigned* __restrict__ ebuf,
              const float4* __restrict__ tbl, float2* __restrict__ tb2,
              float* __restrict__ g) {
  __shared__ float acc[128][4];
  const int b = blockIdx.x, t = threadIdx.x;
  if (t < 128) { acc[t][0] = 0.f; acc[t][1] = 0.f; acc[t][2] = 0.f; }
  __syncthreads();
  const int cnt = bcnt[b * CPAD];
  const unsigned* eb = ebuf + (size_t)b * CAP;
  for (int i = t; i < cnt; i += 256) {
    unsigned r = eb[i];
    float4 v = tbl[r & 0x1FFFFu];
    int d = r >> 17;
    atomicAdd(&acc[d][0], v.x);
    atomicAdd(&acc[d][1], v.y);
    atomicAdd(&acc[d][2], v.z);
  }
  __syncthreads();
  if (t < 128) {
    int node = (b << 7) + t;
    if (node < N_NODES) {
      float4 self = tbl[node];
      float dn = self.z;
      tb2[node] = make_float2(dn * dn * (acc[t][0] + self.x),
                              dn * dn * (acc[t][1] + self.y));
      g[node] = dn * (acc[t][2] + self.z);
    }
  }
}

// ---------------- pass 2, bucket-centric: out = bc + dinv·(yt+Σyt) + g·c1.
// tail = {c1[0],c1[1],bc[0],bc[1]}
__global__ __launch_bounds__(256)
void k_aggr2B(const int* __restrict__ bcnt, const unsigned* __restrict__ ebuf,
              const float2* __restrict__ tb2, const float4* __restrict__ tbl,
              const float* __restrict__ g, const float* __restrict__ tail,
              float* __restrict__ out) {
  __shared__ float acc[128][2];
  const int b = blockIdx.x, t = threadIdx.x;
  if (t < 128) { acc[t][0] = 0.f; acc[t][1] = 0.f; }
  __syncthreads();
  const int cnt = bcnt[b * CPAD];
  const unsigned* eb = ebuf + (size_t)b * CAP;
  for (int i = t; i < cnt; i += 256) {
    unsigned r = eb[i];
    float2 v = tb2[r & 0x1FFFFu];
    int d = r >> 17;
    atomicAdd(&acc[d][0], v.x);
    atomicAdd(&acc[d][1], v.y);
  }
  __syncthreads();
  if (t < 128) {
    int node = (b << 7) + t;
    if (node < N_NODES) {
      float2 self = tb2[node];
      float dn = tbl[node].z;
      float gv = g[node];
      float o0 = dn * (acc[t][0] + self.x) + gv * tail[0] + tail[2];
      float o1 = dn * (acc[t][1] + self.y) + gv * tail[1] + tail[3];
      reinterpret_cast<float2*>(out)[node] = make_float2(o0, o1);
    }
  }
}

// --------------------------------------------- fp32 fallback (small ws) ----
__global__ __launch_bounds__(1024) void k_detect(const int* __restrict__ e,
                                                 int* __restrict__ flag) {
  __shared__ int s;
  if (threadIdx.x == 0) s = 0;
  __syncthreads();
  atomicOr(&s, e[2 * threadIdx.x + 1]);
  __syncthreads();
  if (threadIdx.x == 0) *flag = (s == 0) ? 1 : 0;
}

__global__ __launch_bounds__(256) void k_zero(int* __restrict__ p, int n) {
  int i = blockIdx.x * 256 + threadIdx.x;
  if (i < n) p[i] = 0;
}

__global__ __launch_bounds__(256) void k_count(const int* __restrict__ eidx,
                                               const int* __restrict__ flag,
                                               int* __restrict__ off) {
  int e = blockIdx.x * 256 + threadIdx.x;
  int is64 = *flag;
  if (e < N_EDGES) {
    unsigned d = (unsigned)get_dst(eidx, is64, e);
    if (d < N_NODES) atomicAdd(&off[d], 1);
  }
}

__global__ __launch_bounds__(256) void k_dinv_old(const int* __restrict__ off,
                                                  float* __restrict__ dinv) {
  int i = blockIdx.x * 256 + threadIdx.x;
  if (i < N_NODES) dinv[i] = rsqrtf(1.0f + (float)off[i]);
}

template <int K>
__global__ __launch_bounds__(256)
void k_gemm(const float* __restrict__ A, const float* __restrict__ B,
            const float* __restrict__ bias, const float* __restrict__ scale,
            float* __restrict__ C, const int do_relu) {
  __shared__ float As[64][33];
  const int tid = threadIdx.x;
  const int tx = tid & 15;
  const int ty = tid >> 4;
  const int m0 = blockIdx.x * 64;

  float acc[4][8];
#pragma unroll
  for (int i = 0; i < 4; ++i)
#pragma unroll
    for (int j = 0; j < 8; ++j) acc[i][j] = 0.f;

  const int rs = tid >> 2;
  const int ks = (tid & 3) * 8;

  for (int k0 = 0; k0 < K; k0 += 32) {
    float av8[8];
    const int gm = m0 + rs;
    if (gm < N_NODES) {
      load8(&A[(size_t)gm * K + k0 + ks], av8);
    } else {
#pragma unroll
      for (int j = 0; j < 8; ++j) av8[j] = 0.f;
    }
    __syncthreads();
#pragma unroll
    for (int j = 0; j < 8; ++j) As[rs][ks + j] = av8[j];
    __syncthreads();

    const float* Bp = B + (size_t)k0 * DIM_H + tx * 8;
#pragma unroll 4
    for (int k = 0; k < 32; ++k) {
      float bv[8];
      load8(Bp + (size_t)k * DIM_H, bv);
      float av[4];
#pragma unroll
      for (int rr = 0; rr < 4; ++rr) av[rr] = As[ty * 4 + rr][k];
#pragma unroll
      for (int rr = 0; rr < 4; ++rr)
#pragma unroll
        for (int cc = 0; cc < 8; ++cc)
          acc[rr][cc] = fmaf(av[rr], bv[cc], acc[rr][cc]);
    }
  }

  float bs[8];
  if (bias) {
    load8(bias + tx * 8, bs);
  } else {
#pragma unroll
    for (int j = 0; j < 8; ++j) bs[j] = 0.f;
  }
#pragma unroll
  for (int rr = 0; rr < 4; ++rr) {
    const int gm = m0 + ty * 4 + rr;
    if (gm < N_NODES) {
      float sc = scale ? scale[gm] : 1.0f;
      float v[8];
#pragma unroll
      for (int cc = 0; cc < 8; ++cc) {
        float t = acc[rr][cc] + bs[cc];
        if (do_relu) t = fmaxf(t, 0.f);
        v[cc] = t * sc;
      }
      float* Cp = &C[(size_t)gm * DIM_H + tx * 8];
      reinterpret_cast<float4*>(Cp)[0] = make_float4(v[0], v[1], v[2], v[3]);
      reinterpret_cast<float4*>(Cp)[1] = make_float4(v[4], v[5], v[6], v[7]);
    }
  }
}

__global__ __launch_bounds__(256)
void k_aggr_init(const float* __restrict__ t, const float* __restrict__ dinv,
                 const float* __restrict__ bias, float* __restrict__ h) {
  int idx = blockIdx.x * 256 + threadIdx.x;
  if (idx < N_NODES * DIM_H) {
    int i = idx >> 7;
    int c = idx & 127;
    float d = dinv[i];
    h[idx] = bias[c] + t[idx] * d * d;
  }
}

__global__ __launch_bounds__(256)
void k_aggr_edges(const int* __restrict__ eidx, const int* __restrict__ flag,
                  const float* __restrict__ t, const float* __restrict__ dinv,
                  float* __restrict__ h) {
  int e = blockIdx.x * 2 + (threadIdx.x >> 7);
  int c = threadIdx.x & 127;
  int is64 = *flag;
  if (e < N_EDGES) {
    unsigned s = (unsigned)get_src(eidx, is64, e);
    unsigned d = (unsigned)get_dst(eidx, is64, e);
    if (s < N_NODES && d < N_NODES) {
      float nrm = dinv[s] * dinv[d];
      unsafeAtomicAdd(&h[(size_t)d * DIM_H + c], t[(size_t)s * DIM_H + c] * nrm);
    }
  }
}

__global__ __launch_bounds__(256)
void k_head_f32(const float* __restrict__ h, const float* __restrict__ Wh,
                const float* __restrict__ bh, float* __restrict__ out) {
  int node = blockIdx.x * 4 + (threadIdx.x >> 6);
  int lane = threadIdx.x & 63;
  if (node >= N_NODES) return;
  float h0 = h[(size_t)node * DIM_H + lane];
  float h1 = h[(size_t)node * DIM_H + 64 + lane];
  float s0 = h0 * Wh[lane * 2 + 0] + h1 * Wh[(lane + 64) * 2 + 0];
  float s1 = h0 * Wh[lane * 2 + 1] + h1 * Wh[(lane + 64) * 2 + 1];
#pragma unroll
  for (int off = 32; off > 0; off >>= 1) {
    s0 += __shfl_down(s0, off);
    s1 += __shfl_down(s1, off);
  }
  if (lane == 0) {
    reinterpret_cast<float2*>(out)[node] = make_float2(s0 + bh[0], s1 + bh[1]);
  }
}

// ---------------------------------------------------------------- launch
extern "C" void kernel_launch(void* const* d_in, const int* in_sizes, int n_in,
                              void* d_out, int out_size, void* d_ws, size_t ws_size,
                              hipStream_t stream) {
  (void)in_sizes; (void)n_in; (void)out_size;
  const int* eidx = (const int*)d_in[0];
  const float* x  = (const float*)d_in[1];
  const float* Wi = (const float*)d_in[2];
  const float* bi = (const float*)d_in[3];
  const float* W1 = (const float*)d_in[4];
  const float* b1 = (const float*)d_in[5];
  const float* W2 = (const float*)d_in[6];
  const float* b2 = (const float*)d_in[7];
  const float* Wh = (const float*)d_in[8];
  const float* bh = (const float*)d_in[9];
  float* out = (float*)d_out;

  const int gE  = (N_EDGES + 255) / 256;
  const int gM  = (N_NODES + 63) / 64;       // 1563
  const int gW  = (N_NODES + 3) / 4;

  char* ws = (char*)d_ws;

  const size_t need1 = 16201600;

  if (ws_size >= need1) {
    float*    Wcc  = (float*)(ws + 4096);       // 260 floats
    ushort*   bfWi = (ushort*)(ws + 8192);      // 131072 B -> 139264
    int*      bcnt = (int*)(ws + 139264);       // 50048 B  -> 189312
    float*    dinv = (float*)(ws + 189312);     // 400000 B -> 589312
    float4*   tbl  = (float4*)(ws + 589312);    // 1600000 B -> 2189312
    float2*   tb2  = (float2*)(ws + 2189312);   // 800000 B -> 2989312
    float*    g    = (float*)(ws + 2989312);    // 400000 B -> 3389312
    unsigned* ebuf = (unsigned*)(ws + 3389312); // 12812288 B -> 16201600

    // weight prep (+bcnt zero, block 17) — no deps, first
    k_prep<<<18, 256, 0, stream>>>(Wi, W1, W2, Wh, b1, b2, bh, bfWi, Wcc, bcnt);
    // single-pass binning with block-local counting sort (coalesced writes)
    k_bin1<<<NBLK, 1024, 0, stream>>>(eidx, bcnt, ebuf);
    // per-bucket degree -> dinv
    k_dinvB<<<NBKT, 256, 0, stream>>>(bcnt, ebuf, dinv);
    // z = relu(x@Wi+bi) @ Wcc fused into GEMM epilogue -> tbl (N x float4)
    k_gemm_xz<DIM_IN><<<gM, 256, 0, stream>>>(x, bfWi, bi, Wcc, dinv, tbl);
    // bucket-centric aggregations: LDS atomics, L2-resident gathers
    k_aggr1B<<<NBKT, 256, 0, stream>>>(bcnt, ebuf, tbl, tb2, g);
    k_aggr2B<<<NBKT, 256, 0, stream>>>(bcnt, ebuf, tb2, tbl, g, Wcc + 256, out);
  } else {
    // fallback: fp32 atomic-scatter path (~103 MB)
    const int gN  = (N_NODES + 255) / 256;
    int*   flag = (int*)ws;
    int*   off  = (int*)(ws + 4096);
    float* dinv = (float*)(ws + 404480);
    float* fbA  = (float*)(ws + 804864);
    float* fbB  = (float*)(ws + 804864 + (size_t)N_NODES * DIM_H * 4);
    const int gNH = (N_NODES * DIM_H + 255) / 256;
    const int gE2 = (N_EDGES + 1) / 2;
    k_detect<<<1, 1024, 0, stream>>>(eidx, flag);
    k_zero<<<gN, 256, 0, stream>>>(off, N_NODES);
    k_count<<<gE, 256, 0, stream>>>(eidx, flag, off);
    k_dinv_old<<<gN, 256, 0, stream>>>(off, dinv);

    k_gemm<DIM_IN><<<gM, 256, 0, stream>>>(x, Wi, bi, nullptr, fbA, 1);
    k_gemm<DIM_H><<<gM, 256, 0, stream>>>(fbA, W1, nullptr, nullptr, fbB, 0);
    k_aggr_init<<<gNH, 256, 0, stream>>>(fbB, dinv, b1, fbA);
    k_aggr_edges<<<gE2, 256, 0, stream>>>(eidx, flag, fbB, dinv, fbA);
    k_gemm<DIM_H><<<gM, 256, 0, stream>>>(fbA, W2, nullptr, nullptr, fbB, 0);
    k_aggr_init<<<gNH, 256, 0, stream>>>(fbB, dinv, b2, fbA);
    k_aggr_edges<<<gE2, 256, 0, stream>>>(eidx, flag, fbB, dinv, fbA);
    k_head_f32<<<gW, 256, 0, stream>>>(fbA, Wh, bh, out);
  }
}